// Round 1
// baseline (1590.041 us; speedup 1.0000x reference)
//
#include <hip/hip_runtime.h>
#include <hip/hip_bf16.h>
#include <math.h>

#define NB 8192
#define ND 1024
#define KEPS 1e-8f

// ---------- helpers ----------
__device__ __forceinline__ unsigned int fmono(float f) {
    // monotone float -> uint mapping (order-preserving for all finite floats)
    unsigned int b = __float_as_uint(f);
    return b ^ ((b & 0x80000000u) ? 0xFFFFFFFFu : 0x80000000u);
}

// ---------- kernel 0: init packed argmax accumulators ----------
__global__ void init_packed(unsigned long long* __restrict__ packed) {
    int i = blockIdx.x * blockDim.x + threadIdx.x;
    if (i < NB) packed[i] = 0ull;  // any real candidate (cos >= -1) beats 0
}

// ---------- kernel 1: row L2-normalize ----------
__global__ __launch_bounds__(256) void normalize_k(const float* __restrict__ x,
                                                   float* __restrict__ xn) {
    int row = blockIdx.x;
    int t = threadIdx.x;  // 256 threads, 4 floats each
    const float4* xr = (const float4*)(x + (size_t)row * ND);
    float4 v = xr[t];
    float ss = v.x * v.x + v.y * v.y + v.z * v.z + v.w * v.w;
#pragma unroll
    for (int off = 32; off > 0; off >>= 1) ss += __shfl_down(ss, off, 64);
    __shared__ float sred[4];
    if ((t & 63) == 0) sred[t >> 6] = ss;
    __syncthreads();
    float tot = sred[0] + sred[1] + sred[2] + sred[3];
    float scale = 1.0f / fmaxf(sqrtf(tot), KEPS);
    float4 o;
    o.x = v.x * scale; o.y = v.y * scale; o.z = v.z * scale; o.w = v.w * scale;
    ((float4*)(xn + (size_t)row * ND))[t] = o;
}

// ---------- kernel 2: fused cos-sim GEMM + row argmax ----------
// C[i][j] = dot(xn[i], xn[j]); diagonal treated as -2; per-row (max, argmax)
// merged across column-blocks via packed atomicMax.
#define BM 128
#define BN 128
#define BK 32
#define LDT 132  // 128 + 4 pad: keeps float4 LDS reads 16B-aligned, breaks worst conflicts

__global__ __launch_bounds__(256) void argmax_gemm(const float* __restrict__ xn,
                                                   unsigned long long* __restrict__ packed) {
    __shared__ float As[BK][LDT];  // As[k][r] : rows of the I-tile, transposed
    __shared__ float Bs[BK][LDT];  // Bs[k][c] : rows of the J-tile, transposed

    const int rowBase = blockIdx.y * BM;
    const int colBase = blockIdx.x * BN;
    const int tid = threadIdx.x;
    const int tx = tid & 15;   // 16 col-groups
    const int ty = tid >> 4;   // 16 row-groups

    float acc[8][8];
#pragma unroll
    for (int m = 0; m < 8; ++m)
#pragma unroll
        for (int n = 0; n < 8; ++n) acc[m][n] = 0.0f;

    const float* Abase = xn + (size_t)rowBase * ND;
    const float* Bbase = xn + (size_t)colBase * ND;

    for (int kk = 0; kk < ND; kk += BK) {
        // --- stage: 128 rows x 32 cols per matrix; 4 float4 per thread each ---
        float4 va[4], vb[4];
#pragma unroll
        for (int it = 0; it < 4; ++it) {
            int l = tid + 256 * it;
            int r = l >> 3;        // 0..127
            int kv = l & 7;        // 0..7 (float4 index within the 32-wide k slab)
            va[it] = *(const float4*)(Abase + (size_t)r * ND + kk + kv * 4);
            vb[it] = *(const float4*)(Bbase + (size_t)r * ND + kk + kv * 4);
        }
        __syncthreads();  // previous compute done reading LDS
#pragma unroll
        for (int it = 0; it < 4; ++it) {
            int l = tid + 256 * it;
            int r = l >> 3;
            int kv = l & 7;
            As[kv * 4 + 0][r] = va[it].x;
            As[kv * 4 + 1][r] = va[it].y;
            As[kv * 4 + 2][r] = va[it].z;
            As[kv * 4 + 3][r] = va[it].w;
            Bs[kv * 4 + 0][r] = vb[it].x;
            Bs[kv * 4 + 1][r] = vb[it].y;
            Bs[kv * 4 + 2][r] = vb[it].z;
            Bs[kv * 4 + 3][r] = vb[it].w;
        }
        __syncthreads();

        // --- compute: 32 k-steps, 8x8 outer product per thread ---
#pragma unroll 4
        for (int k = 0; k < BK; ++k) {
            float4 a0 = *(const float4*)&As[k][ty * 8];
            float4 a1 = *(const float4*)&As[k][ty * 8 + 4];
            float4 b0 = *(const float4*)&Bs[k][tx * 8];
            float4 b1 = *(const float4*)&Bs[k][tx * 8 + 4];
            float a[8] = {a0.x, a0.y, a0.z, a0.w, a1.x, a1.y, a1.z, a1.w};
            float b[8] = {b0.x, b0.y, b0.z, b0.w, b1.x, b1.y, b1.z, b1.w};
#pragma unroll
            for (int m = 0; m < 8; ++m)
#pragma unroll
                for (int n = 0; n < 8; ++n) acc[m][n] += a[m] * b[n];
        }
        __syncthreads();
    }

    // --- epilogue: per-row argmax over this block's 128 cols, merge globally ---
#pragma unroll
    for (int m = 0; m < 8; ++m) {
        int gi = rowBase + ty * 8 + m;
        float mx = -3.0f;
        int mc = 0x7FFFFFFF;
#pragma unroll
        for (int n = 0; n < 8; ++n) {
            int gj = colBase + tx * 8 + n;
            float v = (gi == gj) ? -2.0f : acc[m][n];
            if (v > mx) { mx = v; mc = gj; }  // ascending n => first occurrence kept
        }
        // reduce across the 16 lanes (same ty) of this wave
#pragma unroll
        for (int off = 1; off < 16; off <<= 1) {
            float omx = __shfl_xor(mx, off, 64);
            int omc = __shfl_xor(mc, off, 64);
            if (omx > mx || (omx == mx && omc < mc)) { mx = omx; mc = omc; }
        }
        if (tx == 0) {
            unsigned long long p =
                ((unsigned long long)fmono(mx) << 32) |
                (unsigned long long)(~(unsigned int)mc);  // smaller col wins ties
            atomicMax(&packed[gi], p);
        }
    }
}

// ---------- kernel 3: pairwise distance + per-row loss ----------
__global__ __launch_bounds__(256) void dist_k(const float* __restrict__ xn,
                                              const unsigned long long* __restrict__ packed,
                                              float* __restrict__ rowloss) {
    int i = blockIdx.x;
    int t = threadIdx.x;
    unsigned int j = ~(unsigned int)(packed[i] & 0xFFFFFFFFull);
    const float4* a = (const float4*)(xn + (size_t)i * ND);
    const float4* b = (const float4*)(xn + (size_t)j * ND);
    float4 va = a[t], vb = b[t];
    float dx = va.x - vb.x + KEPS;
    float dy = va.y - vb.y + KEPS;
    float dz = va.z - vb.z + KEPS;
    float dw = va.w - vb.w + KEPS;
    float ss = dx * dx + dy * dy + dz * dz + dw * dw;
#pragma unroll
    for (int off = 32; off > 0; off >>= 1) ss += __shfl_down(ss, off, 64);
    __shared__ float sred[4];
    if ((t & 63) == 0) sred[t >> 6] = ss;
    __syncthreads();
    if (t == 0) {
        float tot = sred[0] + sred[1] + sred[2] + sred[3];
        rowloss[i] = -logf(sqrtf(tot) + KEPS);
    }
}

// ---------- kernel 4: mean over rows ----------
__global__ __launch_bounds__(1024) void reduce_k(const float* __restrict__ rowloss,
                                                 float* __restrict__ out) {
    int t = threadIdx.x;
    float s = 0.0f;
#pragma unroll
    for (int k = 0; k < 8; ++k) s += rowloss[t + k * 1024];
#pragma unroll
    for (int off = 32; off > 0; off >>= 1) s += __shfl_down(s, off, 64);
    __shared__ float sred[16];
    if ((t & 63) == 0) sred[t >> 6] = s;
    __syncthreads();
    if (t == 0) {
        float tot = 0.0f;
        for (int k = 0; k < 16; ++k) tot += sred[k];
        out[0] = tot / (float)NB;
    }
}

// ---------- launch ----------
extern "C" void kernel_launch(void* const* d_in, const int* in_sizes, int n_in,
                              void* d_out, int out_size, void* d_ws, size_t ws_size,
                              hipStream_t stream) {
    const float* x = (const float*)d_in[0];
    float* out = (float*)d_out;

    char* ws = (char*)d_ws;
    float* xn = (float*)ws;                                        // 32 MB
    unsigned long long* packed =
        (unsigned long long*)(ws + (size_t)NB * ND * sizeof(float));      // 64 KB
    float* rowloss = (float*)(ws + (size_t)NB * ND * sizeof(float) + NB * 8);  // 32 KB

    init_packed<<<NB / 256, 256, 0, stream>>>(packed);
    normalize_k<<<NB, 256, 0, stream>>>(x, xn);
    argmax_gemm<<<dim3(NB / BN, NB / BM), 256, 0, stream>>>(xn, packed);
    dist_k<<<NB, 256, 0, stream>>>(xn, packed, rowloss);
    reduce_k<<<1, 1024, 0, stream>>>(rowloss, out);
}

// Round 2
// 222.914 us; speedup vs baseline: 7.1330x; 7.1330x over previous
//
#include <hip/hip_runtime.h>
#include <hip/hip_bf16.h>
#include <math.h>

#define NB 8192
#define ND 1024
#define KEPS 1e-8f
#define SLOTS 128   // 64 col-block chunks x 2 wave-halves, exact partition per row

typedef __attribute__((ext_vector_type(8))) __bf16 bf16x8;
typedef __attribute__((ext_vector_type(4))) float f32x4;

// ---------- helpers ----------
__device__ __forceinline__ unsigned int fmono(float f) {
    // monotone float -> uint (order-preserving over all finite floats)
    unsigned int b = __float_as_uint(f);
    return b ^ ((b & 0x80000000u) ? 0xFFFFFFFFu : 0x80000000u);
}

__device__ __forceinline__ unsigned short f2bf(float f) {
    // round-to-nearest-even fp32 -> bf16 (inputs finite)
    union { float f; unsigned int u; } a;
    a.f = f;
    unsigned int lsb = (a.u >> 16) & 1u;
    a.u += 0x7fffu + lsb;
    return (unsigned short)(a.u >> 16);
}

__device__ __forceinline__ void gload_lds16(const void* g, void* l) {
    // async global->LDS, 16B/lane; LDS dest = wave-uniform base + lane*16
    __builtin_amdgcn_global_load_lds(
        (const __attribute__((address_space(1))) unsigned int*)g,
        (__attribute__((address_space(3))) unsigned int*)l, 16, 0, 0);
}

// ---------- kernel 1: row L2-normalize -> bf16 copy (argmax operand only) ----------
__global__ __launch_bounds__(256) void normalize_k(const float* __restrict__ x,
                                                   unsigned short* __restrict__ xnb) {
    int row = blockIdx.x;
    int t = threadIdx.x;  // 256 threads * 4 floats
    float4 v = ((const float4*)(x + (size_t)row * ND))[t];
    float ss = v.x * v.x + v.y * v.y + v.z * v.z + v.w * v.w;
#pragma unroll
    for (int off = 32; off > 0; off >>= 1) ss += __shfl_down(ss, off, 64);
    __shared__ float sred[4];
    if ((t & 63) == 0) sred[t >> 6] = ss;
    __syncthreads();
    float tot = sred[0] + sred[1] + sred[2] + sred[3];
    float scale = 1.0f / fmaxf(sqrtf(tot), KEPS);
    ushort4 o;
    o.x = f2bf(v.x * scale);
    o.y = f2bf(v.y * scale);
    o.z = f2bf(v.z * scale);
    o.w = f2bf(v.w * scale);
    ((ushort4*)xnb)[(size_t)row * (ND / 4) + t] = o;
}

// ---------- kernel 2: bf16 MFMA cos-sim + fused row/col argmax ----------
// m97 structure: 128x128 tile, BK=32, 4 waves (2x2), 4x4 16x16x32 fragments/wave,
// global_load_lds width 16, 2 barriers/K-step. Upper-triangular blocks only;
// each tile contributes row-argmax (rows of by-panel) AND col-argmax (rows of
// bx-panel, via symmetry). Slot partition per row gi (rb = gi/128):
//   row path fills slots {bx*2+wN : bx >= rb}; col path fills {by*2+wM : by < rb}.
__global__ __launch_bounds__(256) void argmax_gemm(const unsigned short* __restrict__ xnb,
                                                   unsigned long long* __restrict__ partial) {
    const int bx = blockIdx.x, by = blockIdx.y;
    if (bx < by) return;  // symmetric: upper triangle only

    __shared__ unsigned short As[128 * 32];  // [row][32 k] row-major, 8 KB
    __shared__ unsigned short Bs[128 * 32];

    const int tid = threadIdx.x;
    const int w = tid >> 6;       // wave 0..3
    const int l = tid & 63;
    const int wM = w >> 1;        // wave row-half
    const int wN = w & 1;         // wave col-half
    const int rowBase = by * 128, colBase = bx * 128;

    f32x4 acc[4][4];
#pragma unroll
    for (int m = 0; m < 4; ++m)
#pragma unroll
        for (int n = 0; n < 4; ++n) acc[m][n] = f32x4{0.f, 0.f, 0.f, 0.f};

    const int lr = l >> 2;        // staged row within 16-row slab
    const int lc = (l & 3) * 8;   // bf16 offset within 32-wide k slab (16B granules)
    const int lm = l & 15;        // fragment row/col lane
    const int ko = (l >> 4) * 8;  // fragment k offset

    for (int kk = 0; kk < ND; kk += 32) {
        // stage: each wave issues 2 x 1KB for A and B (16 rows x 64B each)
#pragma unroll
        for (int q = 0; q < 2; ++q) {
            int rl = (w * 2 + q) * 16 + lr;
            gload_lds16(xnb + (size_t)(rowBase + rl) * ND + kk + lc, &As[(w * 2 + q) * 512]);
            gload_lds16(xnb + (size_t)(colBase + rl) * ND + kk + lc, &Bs[(w * 2 + q) * 512]);
        }
        __syncthreads();  // compiler drains vmcnt(0) before barrier -> tiles ready

        bf16x8 af[4], bf[4];
#pragma unroll
        for (int m = 0; m < 4; ++m)
            af[m] = *(const bf16x8*)&As[(wM * 64 + m * 16 + lm) * 32 + ko];
#pragma unroll
        for (int n = 0; n < 4; ++n)
            bf[n] = *(const bf16x8*)&Bs[(wN * 64 + n * 16 + lm) * 32 + ko];
#pragma unroll
        for (int m = 0; m < 4; ++m)
#pragma unroll
            for (int n = 0; n < 4; ++n)
                acc[m][n] = __builtin_amdgcn_mfma_f32_16x16x32_bf16(af[m], bf[n], acc[m][n], 0, 0, 0);
        __syncthreads();  // protect LDS from next iteration's staging
    }

    // ---- row path: per-row argmax over this tile's 128 cols ----
    // C/D layout (verified m89): col = lane&15, row = (lane>>4)*4 + reg
#pragma unroll
    for (int m = 0; m < 4; ++m) {
#pragma unroll
        for (int r = 0; r < 4; ++r) {
            int gi = rowBase + wM * 64 + m * 16 + (l >> 4) * 4 + r;
            float mx = -3.0f;
            int mc = 0x7FFFFFFF;
#pragma unroll
            for (int n = 0; n < 4; ++n) {
                int gj = colBase + wN * 64 + n * 16 + lm;
                float v = (gi == gj) ? -2.0f : acc[m][n][r];
                if (v > mx) { mx = v; mc = gj; }  // strict > keeps smaller col
            }
#pragma unroll
            for (int off = 1; off < 16; off <<= 1) {  // reduce over lane&15
                float omx = __shfl_xor(mx, off, 64);
                int omc = __shfl_xor(mc, off, 64);
                if (omx > mx || (omx == mx && omc < mc)) { mx = omx; mc = omc; }
            }
            if (lm == 0) {
                unsigned long long p = ((unsigned long long)fmono(mx) << 32) |
                                       (unsigned long long)(~(unsigned int)mc);
                partial[(size_t)gi * SLOTS + bx * 2 + wN] = p;
            }
        }
    }

    // ---- col path: transpose contribution (skip diagonal blocks: redundant) ----
    if (bx > by) {
#pragma unroll
        for (int n = 0; n < 4; ++n) {
            int gj = colBase + wN * 64 + n * 16 + lm;  // row in transpose view
            float mx = -3.0f;
            int mc = 0x7FFFFFFF;
#pragma unroll
            for (int m = 0; m < 4; ++m) {
#pragma unroll
                for (int r = 0; r < 4; ++r) {
                    int gi = rowBase + wM * 64 + m * 16 + (l >> 4) * 4 + r;  // candidate col
                    float v = (gi == gj) ? -2.0f : acc[m][n][r];
                    if (v > mx) { mx = v; mc = gi; }  // ascending gi, strict >
                }
            }
#pragma unroll
            for (int off = 16; off < 64; off <<= 1) {  // reduce over lane>>4 groups
                float omx = __shfl_xor(mx, off, 64);
                int omc = __shfl_xor(mc, off, 64);
                if (omx > mx || (omx == mx && omc < mc)) { mx = omx; mc = omc; }
            }
            if ((l >> 4) == 0) {
                unsigned long long p = ((unsigned long long)fmono(mx) << 32) |
                                       (unsigned long long)(~(unsigned int)mc);
                partial[(size_t)gj * SLOTS + by * 2 + wM] = p;
            }
        }
    }
}

// ---------- kernel 3: reduce slots -> NN index; exact fp32 distance + row loss ----------
__global__ __launch_bounds__(256) void dist_k(const float* __restrict__ x,
                                              const unsigned long long* __restrict__ partial,
                                              float* __restrict__ rowloss) {
    int i = blockIdx.x;
    int t = threadIdx.x;
    unsigned long long p = 0ull;  // loses to any real candidate (fmono(-2)<<32 > 0)
    if (t < SLOTS) p = partial[(size_t)i * SLOTS + t];
#pragma unroll
    for (int off = 1; off < 64; off <<= 1) {
        unsigned long long o = __shfl_xor(p, off, 64);
        if (o > p) p = o;
    }
    __shared__ unsigned long long sp[4];
    __shared__ int sj;
    if ((t & 63) == 0) sp[t >> 6] = p;
    __syncthreads();
    if (t == 0) {
        unsigned long long b = sp[0];
        for (int k = 1; k < 4; ++k)
            if (sp[k] > b) b = sp[k];
        sj = (int)(~(unsigned int)(b & 0xFFFFFFFFull));
    }
    __syncthreads();
    int j = sj;

    // exact fp32: renormalize rows i and j from original x, then PairwiseDistance
    float4 a = ((const float4*)(x + (size_t)i * ND))[t];
    float4 b = ((const float4*)(x + (size_t)j * ND))[t];
    float sa = a.x * a.x + a.y * a.y + a.z * a.z + a.w * a.w;
    float sb = b.x * b.x + b.y * b.y + b.z * b.z + b.w * b.w;
#pragma unroll
    for (int off = 32; off > 0; off >>= 1) {
        sa += __shfl_down(sa, off, 64);
        sb += __shfl_down(sb, off, 64);
    }
    __shared__ float sra[4], srb[4];
    if ((t & 63) == 0) { sra[t >> 6] = sa; srb[t >> 6] = sb; }
    __syncthreads();
    float na = sra[0] + sra[1] + sra[2] + sra[3];
    float nb = srb[0] + srb[1] + srb[2] + srb[3];
    float ia = 1.0f / fmaxf(sqrtf(na), KEPS);
    float ib = 1.0f / fmaxf(sqrtf(nb), KEPS);
    float dx = a.x * ia - b.x * ib + KEPS;
    float dy = a.y * ia - b.y * ib + KEPS;
    float dz = a.z * ia - b.z * ib + KEPS;
    float dw = a.w * ia - b.w * ib + KEPS;
    float ss = dx * dx + dy * dy + dz * dz + dw * dw;
#pragma unroll
    for (int off = 32; off > 0; off >>= 1) ss += __shfl_down(ss, off, 64);
    __shared__ float srd[4];
    if ((t & 63) == 0) srd[t >> 6] = ss;
    __syncthreads();
    if (t == 0) {
        float tot = srd[0] + srd[1] + srd[2] + srd[3];
        rowloss[i] = -logf(sqrtf(tot) + KEPS);
    }
}

// ---------- kernel 4: mean over rows ----------
__global__ __launch_bounds__(1024) void reduce_k(const float* __restrict__ rowloss,
                                                 float* __restrict__ out) {
    int t = threadIdx.x;
    float s = 0.0f;
#pragma unroll
    for (int k = 0; k < 8; ++k) s += rowloss[t + k * 1024];
#pragma unroll
    for (int off = 32; off > 0; off >>= 1) s += __shfl_down(s, off, 64);
    __shared__ float sred[16];
    if ((t & 63) == 0) sred[t >> 6] = s;
    __syncthreads();
    if (t == 0) {
        float tot = 0.0f;
        for (int k = 0; k < 16; ++k) tot += sred[k];
        out[0] = tot / (float)NB;
    }
}

// ---------- launch ----------
extern "C" void kernel_launch(void* const* d_in, const int* in_sizes, int n_in,
                              void* d_out, int out_size, void* d_ws, size_t ws_size,
                              hipStream_t stream) {
    const float* x = (const float*)d_in[0];
    float* out = (float*)d_out;

    char* ws = (char*)d_ws;
    unsigned short* xnb = (unsigned short*)ws;                       // 16 MB bf16 normalized
    unsigned long long* partial =
        (unsigned long long*)(ws + (size_t)NB * ND * 2);             // 8 MB slot table
    float* rowloss = (float*)(ws + (size_t)NB * ND * 2 + (size_t)NB * SLOTS * 8);  // 32 KB

    normalize_k<<<NB, 256, 0, stream>>>(x, xnb);
    argmax_gemm<<<dim3(NB / 128, NB / 128), 256, 0, stream>>>(xnb, partial);
    dist_k<<<NB, 256, 0, stream>>>(x, partial, rowloss);
    reduce_k<<<1, 1024, 0, stream>>>(rowloss, out);
}

// Round 3
// 209.587 us; speedup vs baseline: 7.5865x; 1.0636x over previous
//
#include <hip/hip_runtime.h>
#include <hip/hip_bf16.h>
#include <math.h>

#define NB 8192
#define ND 1024
#define KEPS 1e-8f
#define SLOTS 128
#define NTILE 32          // 8192/256 tile grid
#define NWG 528           // NTILE*(NTILE+1)/2 triangular blocks (= 8*66, XCD-bijective)
#define NKT 16            // K-tiles of 64 (1024/64)

typedef __attribute__((ext_vector_type(8))) __bf16 bf16x8;
typedef __attribute__((ext_vector_type(4))) float f32x4;

// ---------- helpers ----------
__device__ __forceinline__ unsigned int fmono(float f) {
    unsigned int b = __float_as_uint(f);
    return b ^ ((b & 0x80000000u) ? 0xFFFFFFFFu : 0x80000000u);
}
__device__ __forceinline__ unsigned short f2bf(float f) {
    union { float f; unsigned int u; } a;
    a.f = f;
    unsigned int lsb = (a.u >> 16) & 1u;
    a.u += 0x7fffu + lsb;
    return (unsigned short)(a.u >> 16);
}
__device__ __forceinline__ void gload_lds16(const void* g, void* l) {
    __builtin_amdgcn_global_load_lds(
        (const __attribute__((address_space(1))) unsigned int*)g,
        (__attribute__((address_space(3))) unsigned int*)l, 16, 0, 0);
}
__device__ __forceinline__ unsigned long long packmax(float mx, int mc) {
    return ((unsigned long long)fmono(mx) << 32) |
           (unsigned long long)(~(unsigned int)mc);
}

// ---------- kernel 1: row L2-normalize -> bf16 (argmax operand only) ----------
__global__ __launch_bounds__(256) void normalize_k(const float* __restrict__ x,
                                                   unsigned short* __restrict__ xnb) {
    int row = blockIdx.x;
    int t = threadIdx.x;
    float4 v = ((const float4*)(x + (size_t)row * ND))[t];
    float ss = v.x * v.x + v.y * v.y + v.z * v.z + v.w * v.w;
#pragma unroll
    for (int off = 32; off > 0; off >>= 1) ss += __shfl_down(ss, off, 64);
    __shared__ float sred[4];
    if ((t & 63) == 0) sred[t >> 6] = ss;
    __syncthreads();
    float tot = sred[0] + sred[1] + sred[2] + sred[3];
    float scale = 1.0f / fmaxf(sqrtf(tot), KEPS);
    ushort4 o;
    o.x = f2bf(v.x * scale);
    o.y = f2bf(v.y * scale);
    o.z = f2bf(v.z * scale);
    o.w = f2bf(v.w * scale);
    ((ushort4*)xnb)[(size_t)row * (ND / 4) + t] = o;
}

// ---------- kernel 2: 256^2 8-phase bf16 MFMA cos-sim + fused row/col argmax ----------
// LDS layout per buffer (64 KB): [A(32KB): half(2) x subtile(16x1KB)] [B: same].
// Subtile = 16 rows x 32 k bf16, st_16x32 swizzle: byte-in-row ^= ((r>>3)&1)<<5.
// Staged via global_load_lds(16B) with pre-swizzled per-lane SOURCE, linear dest.
#define FENCE_BARRIER() do { asm volatile("" ::: "memory"); \
    __builtin_amdgcn_s_barrier(); asm volatile("" ::: "memory"); } while (0)
#define WAIT_VM2() asm volatile("s_waitcnt vmcnt(2)" ::: "memory")
#define WAIT_VM0() asm volatile("s_waitcnt vmcnt(0)" ::: "memory")

#define STAGE_HALF(H, DBB) do { \
    gload_lds16(sp[H][0], ldsb + (DBB) + ((H) >> 1) * 32768 + ((H) & 1) * 16384 + (0 * 8 + wv) * 1024); \
    gload_lds16(sp[H][1], ldsb + (DBB) + ((H) >> 1) * 32768 + ((H) & 1) * 16384 + (1 * 8 + wv) * 1024); \
    sp[H][0] += 128; sp[H][1] += 128; } while (0)

#define LOAD_A(MH) do { \
    const char* Ab_ = ldsb + cbB + wM * 16384 + laneA; \
    _Pragma("unroll") for (int mi = 0; mi < 4; ++mi) \
    _Pragma("unroll") for (int ks = 0; ks < 2; ++ks) \
        af[mi][ks] = *(const bf16x8*)(Ab_ + ((((MH) * 4 + mi) * 2 + ks) * 1024)); } while (0)

#define LOAD_B(BANK, NH) do { \
    const char* Bb_ = ldsb + cbB + 32768 + (wN >> 1) * 16384 + laneA; \
    _Pragma("unroll") for (int ni = 0; ni < 2; ++ni) \
    _Pragma("unroll") for (int ks = 0; ks < 2; ++ks) \
        BANK[ni][ks] = *(const bf16x8*)(Bb_ + ((((wN & 1) * 4 + (NH) * 2 + ni) * 2 + ks) * 1024)); } while (0)

#define MFMAQ(MH, NH, BANK) do { \
    __builtin_amdgcn_s_setprio(1); \
    _Pragma("unroll") for (int mi = 0; mi < 4; ++mi) \
    _Pragma("unroll") for (int ni = 0; ni < 2; ++ni) { \
        acc[(MH) * 4 + mi][(NH) * 2 + ni] = __builtin_amdgcn_mfma_f32_16x16x32_bf16( \
            af[mi][0], BANK[ni][0], acc[(MH) * 4 + mi][(NH) * 2 + ni], 0, 0, 0); \
        acc[(MH) * 4 + mi][(NH) * 2 + ni] = __builtin_amdgcn_mfma_f32_16x16x32_bf16( \
            af[mi][1], BANK[ni][1], acc[(MH) * 4 + mi][(NH) * 2 + ni], 0, 0, 0); } \
    __builtin_amdgcn_s_setprio(0); } while (0)

__global__ __launch_bounds__(512, 2) void argmax_gemm(const unsigned short* __restrict__ xnb,
                                                      unsigned long long* __restrict__ partial) {
    extern __shared__ char ldsb[];

    // T1: XCD-bijective swizzle (528 = 8*66), then triangular decode
    int wg = (int)blockIdx.x;
    int tile = (wg & 7) * (NWG / 8) + (wg >> 3);
    int by = 0, tr = tile;
    while (tr >= NTILE - by) { tr -= NTILE - by; ++by; }
    const int bx = by + tr;  // bx >= by

    const int rowBase = by * 256, colBase = bx * 256;
    const int tid = (int)threadIdx.x;
    const int wv = tid >> 6;   // wave 0..7
    const int l = tid & 63;
    const int wM = wv >> 2;    // 2 wave-rows (128 rows each)
    const int wN = wv & 3;     // 4 wave-cols (64 cols each)

    // read-side lane byte offset within subtile (includes st_16x32 XOR)
    const int laneA = (l & 15) * 64 + (((l >> 4) * 16) ^ ((l & 8) << 2));

    // stage-side: lane covers r = (l>>2), 16B chunk (l&3); source pre-swizzled
    const int scb = ((l & 3) * 16) ^ ((l >> 5) << 5);
    const int srow = (l >> 2) & 15;

    // 8 stage source pointers: half-tile h (0=A0,1=A1,2=B0,3=B1) x chunk q
    const char* xb = (const char*)xnb;
    const char* sp[4][2];
#pragma unroll
    for (int h = 0; h < 4; ++h)
#pragma unroll
        for (int q = 0; q < 2; ++q) {
            int s = q * 8 + wv;                // subtile this wave's chunk fills
            int rgrp = s >> 1, kgrp = s & 1;
            int panel = (h >> 1) ? colBase : rowBase;
            long long grow = panel + (h & 1) * 128 + rgrp * 16 + srow;
            sp[h][q] = xb + grow * (ND * 2) + kgrp * 64 + scb;
        }

    f32x4 acc[8][4];
#pragma unroll
    for (int m = 0; m < 8; ++m)
#pragma unroll
        for (int n = 0; n < 4; ++n) acc[m][n] = f32x4{0.f, 0.f, 0.f, 0.f};

    // prologue: stage all 4 half-tiles of K-tile 0 into buffer 0
    STAGE_HALF(0, 0); STAGE_HALF(1, 0); STAGE_HALF(2, 0); STAGE_HALF(3, 0);

    int cbB = 0, dbB = 65536;
    for (int c = 0; c < NKT; ++c) {
        const bool pf = (c + 1 < NKT);
        bf16x8 af[4][2], b0[2][2], b1[2][2];
        // phase 0: (mh0, nh0)
        if (pf) { STAGE_HALF(0, dbB); WAIT_VM2(); } else { WAIT_VM0(); }
        FENCE_BARRIER();              // all waves' K-tile-c loads landed
        LOAD_A(0); LOAD_B(b0, 0);
        MFMAQ(0, 0, b0);
        // phase 1: (mh0, nh1) — reuse af
        if (pf) STAGE_HALF(1, dbB);
        LOAD_B(b1, 1);
        MFMAQ(0, 1, b1);
        // phase 2: (mh1, nh1) — reuse b1
        if (pf) STAGE_HALF(2, dbB);
        LOAD_A(1);
        MFMAQ(1, 1, b1);
        // phase 3: (mh1, nh0) — reuse b0
        if (pf) STAGE_HALF(3, dbB);
        MFMAQ(1, 0, b0);
        FENCE_BARRIER();              // all waves done reading buf[cbB]
        int tmp = cbB; cbB = dbB; dbB = tmp;
    }

    // ---- epilogue: fused argmax. C/D: col = lane&15, row = (lane>>4)*4 + reg ----
    // row path: rows of by-panel; slot = 2*by + (bx-by)*4 + wN
#pragma unroll
    for (int m = 0; m < 8; ++m) {
#pragma unroll
        for (int r = 0; r < 4; ++r) {
            int gi = rowBase + wM * 128 + m * 16 + (l >> 4) * 4 + r;
            float mx = -3.0f;
            int mc = 0x7FFFFFFF;
#pragma unroll
            for (int n = 0; n < 4; ++n) {
                int gj = colBase + wN * 64 + n * 16 + (l & 15);
                float v = (gi == gj) ? -2.0f : acc[m][n][r];
                if (v > mx) { mx = v; mc = gj; }
            }
#pragma unroll
            for (int off = 1; off < 16; off <<= 1) {
                float omx = __shfl_xor(mx, off, 64);
                int omc = __shfl_xor(mc, off, 64);
                if (omx > mx || (omx == mx && omc < mc)) { mx = omx; mc = omc; }
            }
            if ((l & 15) == 0)
                partial[(size_t)gi * SLOTS + (2 * by + (bx - by) * 4 + wN)] = packmax(mx, mc);
        }
    }
    // col path (transpose view, bx > by): rows of bx-panel; slot = 2*by + wM
    if (bx > by) {
#pragma unroll
        for (int n = 0; n < 4; ++n) {
            int gj = colBase + wN * 64 + n * 16 + (l & 15);
            float mx = -3.0f;
            int mc = 0x7FFFFFFF;
#pragma unroll
            for (int m = 0; m < 8; ++m) {
#pragma unroll
                for (int r = 0; r < 4; ++r) {
                    int gi = rowBase + wM * 128 + m * 16 + (l >> 4) * 4 + r;
                    float v = (gi == gj) ? -2.0f : acc[m][n][r];
                    if (v > mx) { mx = v; mc = gi; }   // ascending gi, strict >
                }
            }
#pragma unroll
            for (int off = 16; off < 64; off <<= 1) {
                float omx = __shfl_xor(mx, off, 64);
                int omc = __shfl_xor(mc, off, 64);
                if (omx > mx || (omx == mx && omc < mc)) { mx = omx; mc = omc; }
            }
            if ((l >> 4) == 0)
                partial[(size_t)gj * SLOTS + (2 * by + wM)] = packmax(mx, mc);
        }
    }
}

// ---------- kernel 3: reduce valid slots -> NN idx; exact fp32 distance + loss ----------
__global__ __launch_bounds__(256) void dist_k(const float* __restrict__ x,
                                              const unsigned long long* __restrict__ partial,
                                              float* __restrict__ rowloss) {
    int i = blockIdx.x;
    int t = threadIdx.x;
    int nv = SLOTS - 2 * (i >> 8);  // slots [0, 128-2*rowblock) are written; rest poison
    unsigned long long p = 0ull;
    if (t < nv) p = partial[(size_t)i * SLOTS + t];
#pragma unroll
    for (int off = 1; off < 64; off <<= 1) {
        unsigned long long o = __shfl_xor(p, off, 64);
        if (o > p) p = o;
    }
    __shared__ unsigned long long sp_[4];
    __shared__ int sj;
    if ((t & 63) == 0) sp_[t >> 6] = p;
    __syncthreads();
    if (t == 0) {
        unsigned long long b = sp_[0];
        for (int k = 1; k < 4; ++k)
            if (sp_[k] > b) b = sp_[k];
        sj = (int)(~(unsigned int)(b & 0xFFFFFFFFull));
    }
    __syncthreads();
    int j = sj;

    float4 a = ((const float4*)(x + (size_t)i * ND))[t];
    float4 b = ((const float4*)(x + (size_t)j * ND))[t];
    float sa = a.x * a.x + a.y * a.y + a.z * a.z + a.w * a.w;
    float sb = b.x * b.x + b.y * b.y + b.z * b.z + b.w * b.w;
#pragma unroll
    for (int off = 32; off > 0; off >>= 1) {
        sa += __shfl_down(sa, off, 64);
        sb += __shfl_down(sb, off, 64);
    }
    __shared__ float sra[4], srb[4];
    if ((t & 63) == 0) { sra[t >> 6] = sa; srb[t >> 6] = sb; }
    __syncthreads();
    float na = sra[0] + sra[1] + sra[2] + sra[3];
    float nb = srb[0] + srb[1] + srb[2] + srb[3];
    float ia = 1.0f / fmaxf(sqrtf(na), KEPS);
    float ib = 1.0f / fmaxf(sqrtf(nb), KEPS);
    float dx = a.x * ia - b.x * ib + KEPS;
    float dy = a.y * ia - b.y * ib + KEPS;
    float dz = a.z * ia - b.z * ib + KEPS;
    float dw = a.w * ia - b.w * ib + KEPS;
    float ss = dx * dx + dy * dy + dz * dz + dw * dw;
#pragma unroll
    for (int off = 32; off > 0; off >>= 1) ss += __shfl_down(ss, off, 64);
    __shared__ float srd[4];
    if ((t & 63) == 0) srd[t >> 6] = ss;
    __syncthreads();
    if (t == 0) {
        float tot = srd[0] + srd[1] + srd[2] + srd[3];
        rowloss[i] = -logf(sqrtf(tot) + KEPS);
    }
}

// ---------- kernel 4: mean over rows ----------
__global__ __launch_bounds__(1024) void reduce_k(const float* __restrict__ rowloss,
                                                 float* __restrict__ out) {
    int t = threadIdx.x;
    float s = 0.0f;
#pragma unroll
    for (int k = 0; k < 8; ++k) s += rowloss[t + k * 1024];
#pragma unroll
    for (int off = 32; off > 0; off >>= 1) s += __shfl_down(s, off, 64);
    __shared__ float sred[16];
    if ((t & 63) == 0) sred[t >> 6] = s;
    __syncthreads();
    if (t == 0) {
        float tot = 0.0f;
        for (int k = 0; k < 16; ++k) tot += sred[k];
        out[0] = tot / (float)NB;
    }
}

// ---------- launch ----------
extern "C" void kernel_launch(void* const* d_in, const int* in_sizes, int n_in,
                              void* d_out, int out_size, void* d_ws, size_t ws_size,
                              hipStream_t stream) {
    const float* x = (const float*)d_in[0];
    float* out = (float*)d_out;

    char* ws = (char*)d_ws;
    unsigned short* xnb = (unsigned short*)ws;                        // 16 MB
    unsigned long long* partial =
        (unsigned long long*)(ws + (size_t)NB * ND * 2);              // 8 MB
    float* rowloss = (float*)(ws + (size_t)NB * ND * 2 + (size_t)NB * SLOTS * 8);

    // allow 128 KiB dynamic LDS (idempotent; host-side, not a stream op)
    (void)hipFuncSetAttribute((const void*)argmax_gemm,
                              hipFuncAttributeMaxDynamicSharedMemorySize, 131072);

    normalize_k<<<NB, 256, 0, stream>>>(x, xnb);
    argmax_gemm<<<NWG, 512, 131072, stream>>>(xnb, partial);
    dist_k<<<NB, 256, 0, stream>>>(x, partial, rowloss);
    reduce_k<<<1, 1024, 0, stream>>>(rowloss, out);
}